// Round 10
// baseline (127.641 us; speedup 1.0000x reference)
//
#include <hip/hip_runtime.h>
#include <hip/hip_bf16.h>
#include <math.h>

#define NR 8
#define NB 8
#define NH 32
#define NKVH 8
#define NG 4
#define ND 128
#define NDV 128
#define NPAGE 2048
#define KSTR (NKVH*ND)        // 1024 floats per page (all kvh slices)
#define NCH 8                 // page-chunks per rank
#define CHUNK 256             // pages per chunk
#define NPART (NR*NCH)        // 64 partial slots
#define PSTRIDE (NB*NKVH*NG)  // 256 output rows
#define QSCALE 0.088388347648318447f
#define DEFER_THR 8.0f

typedef __attribute__((ext_vector_type(8))) short bf16x8;
typedef __attribute__((ext_vector_type(4))) float f32x4;

static __device__ __forceinline__ short f2bf(float x) {
  __hip_bfloat16 h = __float2bfloat16(x);
  return __builtin_bit_cast(short, h);
}

// ---------------- histogram: cntf[r][b][pg] = (float) multiplicity
__global__ __launch_bounds__(256) void build_counts(
    const int* __restrict__ kv_lens, const int* __restrict__ bt_all,
    float* __restrict__ cntf) {
  const int rb = blockIdx.x;             // r*NB + b
  __shared__ int h[NPAGE];
  for (int i = threadIdx.x; i < NPAGE; i += 256) h[i] = 0;
  __syncthreads();
  const int len = kv_lens[rb];
  const int* bt = bt_all + (size_t)rb * NPAGE;
  for (int i = threadIdx.x; i < len; i += 256) atomicAdd(&h[bt[i]], 1);
  __syncthreads();
  float* o = cntf + (size_t)rb * NPAGE;
  for (int i = threadIdx.x; i < NPAGE; i += 256) o[i] = (float)h[i];
}

// ---------------- MFMA weighted-stream attention partials
// block = (r, kvh, chunk, gp); 4 waves, each owns 64 pages (4 tiles of 16).
// Per tile: S[16 qrows][16 pages] = Q(bf16) x K(bf16)^T via 4x mfma_16x16x32,
// batched defer-max softmax (counts as weights), PV in fp32 VALU from global V.
// Score layout (D-frag, m89-verified): page = lane&15, qrow = (lane>>4)*4+reg.
// PV layout: qrow = lane&15, dv dims = (lane>>4)*32 .. +31.
// qrow = g'*8 + b  (b = qrow&7, g = gp*2 + (qrow>>3)).
__global__ __launch_bounds__(256, 2) void attn_partial(
    const float* __restrict__ q,
    const float* __restrict__ k_cache,
    const float* __restrict__ v_cache,
    const float* __restrict__ cntf,
    float* __restrict__ ws_out,   // [NPART][NB][NKVH][NG][NDV]
    float* __restrict__ ws_lse)   // [NPART][NB][NKVH][NG]
{
  const int bid   = blockIdx.x;
  const int r     = bid & 7;              // XCD swizzle: rank pinned per XCD
  const int kvh   = (bid >> 3) & 7;
  const int chunk = (bid >> 6) & 7;
  const int gp    = bid >> 9;             // heads {2gp, 2gp+1}

  const int tid  = threadIdx.x;
  const int wid  = tid >> 6;
  const int lane = tid & 63;
  const int col  = lane & 15;     // score: page-in-tile | PV: qrow
  const int hq   = lane >> 4;     // quarter 0..3

  __shared__ float Plds[4][16][17];       // [wid][pg][qr] padded
  __shared__ float Sclds[4][16];          // rescale factors
  __shared__ float Sml[4][16][2];         // {m,l} per qrow per wave
  __shared__ float Sacc[4][16][NDV + 4];  // O partial per wave (padded row)

  // ---- Q A-frags (bf16, pre-scaled): row m = col(=lane&15) = qrow,
  // dims k = st*32 + hq*8 + j (consecutive 8) — matches B-frag k slices.
  bf16x8 qf[4];
  {
    const int qrow = col;
    const int b = qrow & 7;
    const int g = gp * 2 + (qrow >> 3);
    const float* qp = q + ((size_t)b * NH + kvh * NG + g) * ND + hq * 8;
#pragma unroll
    for (int st = 0; st < 4; ++st) {
      const float4 t0 = *(const float4*)(qp + st * 32);
      const float4 t1 = *(const float4*)(qp + st * 32 + 4);
      bf16x8 f;
      f[0] = f2bf(t0.x * QSCALE); f[1] = f2bf(t0.y * QSCALE);
      f[2] = f2bf(t0.z * QSCALE); f[3] = f2bf(t0.w * QSCALE);
      f[4] = f2bf(t1.x * QSCALE); f[5] = f2bf(t1.y * QSCALE);
      f[6] = f2bf(t1.z * QSCALE); f[7] = f2bf(t1.w * QSCALE);
      qf[st] = f;
    }
  }

  const int pg0w = chunk * CHUNK + wid * 64;   // wave's first page
  const float* Kb = k_cache + (size_t)r * NPAGE * KSTR + kvh * ND;
  const float* Vb = v_cache + (size_t)r * NPAGE * KSTR + kvh * NDV;

  float m[4], l[4];
#pragma unroll
  for (int g4 = 0; g4 < 4; ++g4) { m[g4] = -INFINITY; l[g4] = 0.f; }
  f32x4 O[8];
#pragma unroll
  for (int i = 0; i < 8; ++i) O[i] = (f32x4){0.f, 0.f, 0.f, 0.f};

#pragma unroll 1
  for (int t = 0; t < 4; ++t) {
    const int pgt = pg0w + t * 16;

    // ---- QK^T: 4 MFMAs over the 128-dim
    const float* kp = Kb + (size_t)(pgt + col) * KSTR + hq * 8;
    f32x4 acc = (f32x4){0.f, 0.f, 0.f, 0.f};
#pragma unroll
    for (int st = 0; st < 4; ++st) {
      const float4 a0 = *(const float4*)(kp + st * 32);
      const float4 a1 = *(const float4*)(kp + st * 32 + 4);
      bf16x8 kf;
      kf[0] = f2bf(a0.x); kf[1] = f2bf(a0.y); kf[2] = f2bf(a0.z); kf[3] = f2bf(a0.w);
      kf[4] = f2bf(a1.x); kf[5] = f2bf(a1.y); kf[6] = f2bf(a1.z); kf[7] = f2bf(a1.w);
      acc = __builtin_amdgcn_mfma_f32_16x16x32_bf16(qf[st], kf, acc, 0, 0, 0);
    }

    // ---- counts (weights) for my 4 (qrow, page) cells
    float cw[4];
#pragma unroll
    for (int rg = 0; rg < 4; ++rg) {
      const int qr = hq * 4 + rg;
      cw[rg] = cntf[((size_t)(r * NB + (qr & 7))) * NPAGE + pgt + col];
    }

    // ---- batched softmax: row-max butterfly over the 16 page-lanes
    float s[4], tm[4];
#pragma unroll
    for (int rg = 0; rg < 4; ++rg) { s[rg] = acc[rg]; tm[rg] = acc[rg]; }
#pragma unroll
    for (int mk = 1; mk <= 8; mk <<= 1)
#pragma unroll
      for (int rg = 0; rg < 4; ++rg) tm[rg] = fmaxf(tm[rg], __shfl_xor(tm[rg], mk));

    bool need = false;
#pragma unroll
    for (int rg = 0; rg < 4; ++rg) need |= (tm[rg] > m[rg] + DEFER_THR);
    const bool doresc = __any(need);
    if (doresc) {                       // rare: once per tile at most
#pragma unroll
      for (int rg = 0; rg < 4; ++rg) {
        const float mn = fmaxf(m[rg], tm[rg]);
        const float sc = __expf(m[rg] - mn);   // first tile: exp(-inf)=0
        m[rg] = mn; l[rg] *= sc;
        if (col == 0) Sclds[wid][hq * 4 + rg] = sc;
      }
    }

    float p[4], ts[4];
#pragma unroll
    for (int rg = 0; rg < 4; ++rg) {
      p[rg] = cw[rg] * __expf(s[rg] - m[rg]);
      ts[rg] = p[rg];
    }
#pragma unroll
    for (int mk = 1; mk <= 8; mk <<= 1)
#pragma unroll
      for (int rg = 0; rg < 4; ++rg) ts[rg] += __shfl_xor(ts[rg], mk);
#pragma unroll
    for (int rg = 0; rg < 4; ++rg) {
      l[rg] += ts[rg];
      Plds[wid][col][hq * 4 + rg] = p[rg];   // P -> LDS (score layout write)
    }

    if (doresc) {                       // rescale O (PV layout, qr = col)
      const float so = Sclds[wid][col];
#pragma unroll
      for (int i = 0; i < 8; ++i) {
        O[i].x *= so; O[i].y *= so; O[i].z *= so; O[i].w *= so;
      }
    }

    // ---- PV (fp32 VALU): V direct from global (L2/L3-resident stream)
    const float* vpb = Vb + (size_t)pgt * KSTR + hq * 32;
#pragma unroll 2
    for (int pg = 0; pg < 16; ++pg) {
      const float pw = Plds[wid][pg][col];
      const float* vp = vpb + (size_t)pg * KSTR;
#pragma unroll
      for (int i = 0; i < 8; ++i) {
        const float4 v4 = *(const float4*)(vp + i * 4);
        O[i].x += pw * v4.x; O[i].y += pw * v4.y;
        O[i].z += pw * v4.z; O[i].w += pw * v4.w;
      }
    }
  }

  // ---- stash per-wave state
  if (col == 0) {
#pragma unroll
    for (int rg = 0; rg < 4; ++rg) {
      Sml[wid][hq * 4 + rg][0] = m[rg];
      Sml[wid][hq * 4 + rg][1] = l[rg];
    }
  }
#pragma unroll
  for (int i = 0; i < 8; ++i)
    *(f32x4*)&Sacc[wid][col][hq * 32 + i * 4] = O[i];
  __syncthreads();

  // ---- 4-way wave merge, normalize, write partial
  const int qr = tid >> 4;        // 0..15
  const int db = tid & 15;        // 8 dims each
  float M = -INFINITY;
#pragma unroll
  for (int w = 0; w < 4; ++w) M = fmaxf(M, Sml[w][qr][0]);
  float wgt[4];
  float L = 0.f;
#pragma unroll
  for (int w = 0; w < 4; ++w) {
    const float mw = Sml[w][qr][0];
    wgt[w] = (mw > -1e37f) ? __expf(mw - M) : 0.f;
    L += Sml[w][qr][1] * wgt[w];
  }
  const float inv = (L > 0.f) ? 1.f / L : 0.f;

  const int pi = r * NCH + chunk;
  const int b  = qr & 7;
  const int g  = gp * 2 + (qr >> 3);
  const size_t prow = (((size_t)pi * NB + b) * NKVH + kvh) * NG + g;
  float* orow = ws_out + prow * NDV + db * 8;
#pragma unroll
  for (int x = 0; x < 2; ++x) {
    float4 o = make_float4(0.f, 0.f, 0.f, 0.f);
#pragma unroll
    for (int w = 0; w < 4; ++w) {
      const float* s4 = &Sacc[w][qr][db * 8 + x * 4];
      o.x += s4[0] * wgt[w]; o.y += s4[1] * wgt[w];
      o.z += s4[2] * wgt[w]; o.w += s4[3] * wgt[w];
    }
    o.x *= inv; o.y *= inv; o.z *= inv; o.w *= inv;
    *(float4*)(orow + x * 4) = o;
  }
  if (db == 0) ws_lse[prow] = (L > 0.f) ? (M + __logf(L)) : -1e30f;
}

// ---------------- combine over NPART partials per (b,kvh,g)
__global__ __launch_bounds__(128) void attn_combine(
    const float* __restrict__ ws_out,
    const float* __restrict__ ws_lse,
    float* __restrict__ out)
{
  const int bkg = blockIdx.x;
  const int d   = threadIdx.x;

  float mg = -INFINITY;
#pragma unroll 16
  for (int p = 0; p < NPART; ++p)
    mg = fmaxf(mg, ws_lse[p * PSTRIDE + bkg]);

  float denom = 0.f, acc = 0.f;
#pragma unroll 8
  for (int p = 0; p < NPART; ++p) {
    const float e = __expf(ws_lse[p * PSTRIDE + bkg] - mg);
    denom += e;
    acc += e * ws_out[((size_t)p * PSTRIDE + bkg) * NDV + d];
  }
  out[(size_t)bkg * NDV + d] = acc / denom;
}

extern "C" void kernel_launch(void* const* d_in, const int* in_sizes, int n_in,
                              void* d_out, int out_size, void* d_ws, size_t ws_size,
                              hipStream_t stream) {
  const float* q        = (const float*)d_in[0];
  const float* k_cache  = (const float*)d_in[1];
  const float* v_cache  = (const float*)d_in[2];
  const int*   kv_lens  = (const int*)d_in[3];
  const int*   bt       = (const int*)d_in[4];
  float* out = (float*)d_out;

  float* ws_out = (float*)d_ws;                                   // 8.39 MB
  float* ws_lse = ws_out + (size_t)NPART * PSTRIDE * NDV;         // 64 KB
  float* cntf   = ws_lse + NPART * PSTRIDE;                       // 512 KB

  build_counts<<<NR * NB, 256, 0, stream>>>(kv_lens, bt, cntf);
  attn_partial<<<NR * NKVH * NCH * 2, 256, 0, stream>>>(
      q, k_cache, v_cache, cntf, ws_out, ws_lse);
  attn_combine<<<NB * NKVH * NG, NDV, 0, stream>>>(ws_out, ws_lse, out);
}

// Round 11
// 72.147 us; speedup vs baseline: 1.7692x; 1.7692x over previous
//
#include <hip/hip_runtime.h>
#include <hip/hip_bf16.h>
#include <math.h>

#define NR 8
#define NB 8
#define NH 32
#define NKVH 8
#define NG 4
#define ND 128
#define NDV 128
#define NPAGE 2048
#define KSTR (NKVH*ND)        // 1024 floats per page (all kvh slices)
#define NCH 8                 // page-chunks per rank
#define CHUNK 256             // pages per chunk
#define NPART (NR*NCH)        // 64 partial slots
#define PSTRIDE (NB*NKVH*NG)  // 256 output rows
#define QSCALE 0.088388347648318447f
#define DEFER_THR 8.0f

typedef __attribute__((ext_vector_type(8))) short bf16x8;
typedef __attribute__((ext_vector_type(4))) float f32x4;

static __device__ __forceinline__ short f2bf(float x) {
  __hip_bfloat16 h = __float2bfloat16(x);
  return __builtin_bit_cast(short, h);
}

// async global->LDS, 16B per lane; LDS dest = wave-uniform base + lane*16
static __device__ __forceinline__ void gload_lds16(const float* g, float* l) {
  __builtin_amdgcn_global_load_lds(
      (__attribute__((address_space(1))) void*)g,
      (__attribute__((address_space(3))) void*)l, 16, 0, 0);
}

// ---------------- histogram: cntf[r][b][pg] = (float) multiplicity
__global__ __launch_bounds__(256) void build_counts(
    const int* __restrict__ kv_lens, const int* __restrict__ bt_all,
    float* __restrict__ cntf) {
  const int rb = blockIdx.x;             // r*NB + b
  __shared__ int h[NPAGE];
  for (int i = threadIdx.x; i < NPAGE; i += 256) h[i] = 0;
  __syncthreads();
  const int len = kv_lens[rb];
  const int* bt = bt_all + (size_t)rb * NPAGE;
  for (int i = threadIdx.x; i < len; i += 256) atomicAdd(&h[bt[i]], 1);
  __syncthreads();
  float* o = cntf + (size_t)rb * NPAGE;
  for (int i = threadIdx.x; i < NPAGE; i += 256) o[i] = (float)h[i];
}

// ---------------- MFMA weighted-stream attention partials, 2-deep pipelined.
// block = (r, kvh, chunk, gp); 4 waves, each owns 64 pages (4 tiles of 16).
// Pipeline per tile: issue {stage V(t+1) -> LDS, K(t+1) -> regs, counts(t+1)}
// = 20 VMEM ops, then s_waitcnt vmcnt(20) (counted, not 0) -> tile t ready
// while tile t+1 stays in flight. Wave-private LDS buffers: no barriers.
__global__ __launch_bounds__(256, 1) void attn_partial(
    const float* __restrict__ q,
    const float* __restrict__ k_cache,
    const float* __restrict__ v_cache,
    const float* __restrict__ cntf,
    float* __restrict__ ws_out,   // [NPART][NB][NKVH][NG][NDV]
    float* __restrict__ ws_lse)   // [NPART][NB][NKVH][NG]
{
  const int bid   = blockIdx.x;
  const int r     = bid & 7;              // XCD swizzle: rank pinned per XCD
  const int kvh   = (bid >> 3) & 7;
  const int chunk = (bid >> 6) & 7;
  const int gp    = bid >> 9;             // heads {2gp, 2gp+1}

  const int tid  = threadIdx.x;
  const int wid  = tid >> 6;
  const int lane = tid & 63;
  const int col  = lane & 15;     // score: page-in-tile | PV: qrow
  const int hq   = lane >> 4;     // quarter 0..3

  // V double-buffer (wave-private), union'd with the post-loop Sacc merge
  // buffer (disjoint lifetimes): 64 KB.
  __shared__ float UN[4][2][2048];
  __shared__ float Plds[4][16][17];
  __shared__ float Sclds[4][16];
  __shared__ float Sml[4][16][2];

  // ---- Q A-frags (bf16, pre-scaled)
  bf16x8 qf[4];
  {
    const int qrow = col;
    const int b = qrow & 7;
    const int g = gp * 2 + (qrow >> 3);
    const float* qp = q + ((size_t)b * NH + kvh * NG + g) * ND + hq * 8;
#pragma unroll
    for (int st = 0; st < 4; ++st) {
      const float4 t0 = *(const float4*)(qp + st * 32);
      const float4 t1 = *(const float4*)(qp + st * 32 + 4);
      bf16x8 f;
      f[0] = f2bf(t0.x * QSCALE); f[1] = f2bf(t0.y * QSCALE);
      f[2] = f2bf(t0.z * QSCALE); f[3] = f2bf(t0.w * QSCALE);
      f[4] = f2bf(t1.x * QSCALE); f[5] = f2bf(t1.y * QSCALE);
      f[6] = f2bf(t1.z * QSCALE); f[7] = f2bf(t1.w * QSCALE);
      qf[st] = f;
    }
  }

  const int pg0w = chunk * CHUNK + wid * 64;   // wave's first page
  const float* Kb = k_cache + (size_t)r * NPAGE * KSTR + kvh * ND;
  const float* Vb = v_cache + (size_t)r * NPAGE * KSTR + kvh * NDV;

  // prefetch macros: 8 stage + 8 K + 4 cw = 20 VMEM ops per tile
#define STAGE_V(bf, pgt)                                                     \
  {                                                                          \
    _Pragma("unroll")                                                        \
    for (int i = 0; i < 8; ++i) {                                            \
      const float* s_ =                                                      \
          Vb + (size_t)((pgt) + 2 * i + (lane >> 5)) * KSTR + (lane & 31) * 4; \
      gload_lds16(s_, &UN[wid][bf][i * 256]);                                \
    }                                                                        \
  }
#define KLOAD(dst, pgt)                                                      \
  {                                                                          \
    const float* kp_ = Kb + (size_t)((pgt) + col) * KSTR + hq * 8;           \
    _Pragma("unroll")                                                        \
    for (int st = 0; st < 4; ++st) {                                         \
      dst[2 * st]     = *(const float4*)(kp_ + st * 32);                     \
      dst[2 * st + 1] = *(const float4*)(kp_ + st * 32 + 4);                 \
    }                                                                        \
  }
#define CWLOAD(dst, pgt)                                                     \
  {                                                                          \
    _Pragma("unroll")                                                        \
    for (int rg = 0; rg < 4; ++rg)                                           \
      dst[rg] = cntf[((size_t)(r * NB + ((hq * 4 + rg) & 7))) * NPAGE +      \
                     (pgt) + col];                                           \
  }

  float4 kr[2][8];
  float  cwl[2][4];

  // prologue: prefetch tile 0
  STAGE_V(0, pg0w);
  KLOAD(kr[0], pg0w);
  CWLOAD(cwl[0], pg0w);

  float m[4], l[4];
#pragma unroll
  for (int g4 = 0; g4 < 4; ++g4) { m[g4] = -INFINITY; l[g4] = 0.f; }
  f32x4 O[8];
#pragma unroll
  for (int i = 0; i < 8; ++i) O[i] = (f32x4){0.f, 0.f, 0.f, 0.f};

#pragma unroll
  for (int t = 0; t < 4; ++t) {
    const int pgt = pg0w + t * 16;
    const int bf  = t & 1;

    if (t < 3) {                         // prefetch t+1, then counted wait
      STAGE_V(bf ^ 1, pgt + 16);
      KLOAD(kr[(t + 1) & 1], pgt + 16);
      CWLOAD(cwl[(t + 1) & 1], pgt + 16);
      asm volatile("s_waitcnt vmcnt(20)" ::: "memory");
    } else {
      asm volatile("s_waitcnt vmcnt(0)" ::: "memory");
    }

    // ---- QK^T: 4 MFMAs (K from prefetched regs, cvt to bf16 now)
    f32x4 acc = (f32x4){0.f, 0.f, 0.f, 0.f};
#pragma unroll
    for (int st = 0; st < 4; ++st) {
      const float4 a0 = kr[bf][2 * st];
      const float4 a1 = kr[bf][2 * st + 1];
      bf16x8 kf;
      kf[0] = f2bf(a0.x); kf[1] = f2bf(a0.y); kf[2] = f2bf(a0.z); kf[3] = f2bf(a0.w);
      kf[4] = f2bf(a1.x); kf[5] = f2bf(a1.y); kf[6] = f2bf(a1.z); kf[7] = f2bf(a1.w);
      acc = __builtin_amdgcn_mfma_f32_16x16x32_bf16(qf[st], kf, acc, 0, 0, 0);
    }

    // ---- batched softmax (counts as weights), defer-max
    float s[4], tm[4];
#pragma unroll
    for (int rg = 0; rg < 4; ++rg) { s[rg] = acc[rg]; tm[rg] = acc[rg]; }
#pragma unroll
    for (int mk = 1; mk <= 8; mk <<= 1)
#pragma unroll
      for (int rg = 0; rg < 4; ++rg) tm[rg] = fmaxf(tm[rg], __shfl_xor(tm[rg], mk));

    bool need = false;
#pragma unroll
    for (int rg = 0; rg < 4; ++rg) need |= (tm[rg] > m[rg] + DEFER_THR);
    const bool doresc = __any(need);
    if (doresc) {
#pragma unroll
      for (int rg = 0; rg < 4; ++rg) {
        const float mn = fmaxf(m[rg], tm[rg]);
        const float sc = __expf(m[rg] - mn);   // first tile: exp(-inf)=0
        m[rg] = mn; l[rg] *= sc;
        if (col == 0) Sclds[wid][hq * 4 + rg] = sc;
      }
    }

    float p[4], ts[4];
#pragma unroll
    for (int rg = 0; rg < 4; ++rg) {
      p[rg] = cwl[bf][rg] * __expf(s[rg] - m[rg]);
      ts[rg] = p[rg];
    }
#pragma unroll
    for (int mk = 1; mk <= 8; mk <<= 1)
#pragma unroll
      for (int rg = 0; rg < 4; ++rg) ts[rg] += __shfl_xor(ts[rg], mk);
#pragma unroll
    for (int rg = 0; rg < 4; ++rg) {
      l[rg] += ts[rg];
      Plds[wid][col][hq * 4 + rg] = p[rg];
    }

    if (doresc) {                        // rescale O (PV layout, qrow = col)
      const float so = Sclds[wid][col];
#pragma unroll
      for (int i = 0; i < 8; ++i) {
        O[i].x *= so; O[i].y *= so; O[i].z *= so; O[i].w *= so;
      }
    }

    // ---- PV from LDS-staged V (no miss latency)
#pragma unroll 2
    for (int pg = 0; pg < 16; ++pg) {
      const float pw = Plds[wid][pg][col];
      const float* vl = &UN[wid][bf][pg * 128 + hq * 32];
#pragma unroll
      for (int i = 0; i < 8; ++i) {
        const f32x4 v4 = *(const f32x4*)(vl + i * 4);
        O[i].x += pw * v4.x; O[i].y += pw * v4.y;
        O[i].z += pw * v4.z; O[i].w += pw * v4.w;
      }
    }
  }

  // ---- merge: overlay Sacc onto the (now dead) V buffers
  __syncthreads();                       // all waves done reading UN
  float* Sacc = &UN[0][0][0];            // [w][qr] rows of 132 floats
  if (col == 0) {
#pragma unroll
    for (int rg = 0; rg < 4; ++rg) {
      Sml[wid][hq * 4 + rg][0] = m[rg];
      Sml[wid][hq * 4 + rg][1] = l[rg];
    }
  }
#pragma unroll
  for (int i = 0; i < 8; ++i)
    *(f32x4*)&Sacc[(wid * 16 + col) * 132 + hq * 32 + i * 4] = O[i];
  __syncthreads();

  // ---- 4-way wave merge, normalize, write partial
  const int qr = tid >> 4;        // 0..15
  const int db = tid & 15;        // 8 dims each
  float M = -INFINITY;
#pragma unroll
  for (int w = 0; w < 4; ++w) M = fmaxf(M, Sml[w][qr][0]);
  float wgt[4];
  float L = 0.f;
#pragma unroll
  for (int w = 0; w < 4; ++w) {
    const float mw = Sml[w][qr][0];
    wgt[w] = (mw > -1e37f) ? __expf(mw - M) : 0.f;
    L += Sml[w][qr][1] * wgt[w];
  }
  const float inv = (L > 0.f) ? 1.f / L : 0.f;

  const int pi = r * NCH + chunk;
  const int b  = qr & 7;
  const int g  = gp * 2 + (qr >> 3);
  const size_t prow = (((size_t)pi * NB + b) * NKVH + kvh) * NG + g;
  float* orow = ws_out + prow * NDV + db * 8;
#pragma unroll
  for (int x = 0; x < 2; ++x) {
    float4 o = make_float4(0.f, 0.f, 0.f, 0.f);
#pragma unroll
    for (int w = 0; w < 4; ++w) {
      const float* s4 = &Sacc[(w * 16 + qr) * 132 + db * 8 + x * 4];
      o.x += s4[0] * wgt[w]; o.y += s4[1] * wgt[w];
      o.z += s4[2] * wgt[w]; o.w += s4[3] * wgt[w];
    }
    o.x *= inv; o.y *= inv; o.z *= inv; o.w *= inv;
    *(float4*)(orow + x * 4) = o;
  }
  if (db == 0) ws_lse[prow] = (L > 0.f) ? (M + __logf(L)) : -1e30f;
}

// ---------------- combine over NPART partials per (b,kvh,g)
__global__ __launch_bounds__(128) void attn_combine(
    const float* __restrict__ ws_out,
    const float* __restrict__ ws_lse,
    float* __restrict__ out)
{
  const int bkg = blockIdx.x;
  const int d   = threadIdx.x;

  float mg = -INFINITY;
#pragma unroll 16
  for (int p = 0; p < NPART; ++p)
    mg = fmaxf(mg, ws_lse[p * PSTRIDE + bkg]);

  float denom = 0.f, acc = 0.f;
#pragma unroll 8
  for (int p = 0; p < NPART; ++p) {
    const float e = __expf(ws_lse[p * PSTRIDE + bkg] - mg);
    denom += e;
    acc += e * ws_out[((size_t)p * PSTRIDE + bkg) * NDV + d];
  }
  out[(size_t)bkg * NDV + d] = acc / denom;
}

extern "C" void kernel_launch(void* const* d_in, const int* in_sizes, int n_in,
                              void* d_out, int out_size, void* d_ws, size_t ws_size,
                              hipStream_t stream) {
  const float* q        = (const float*)d_in[0];
  const float* k_cache  = (const float*)d_in[1];
  const float* v_cache  = (const float*)d_in[2];
  const int*   kv_lens  = (const int*)d_in[3];
  const int*   bt       = (const int*)d_in[4];
  float* out = (float*)d_out;

  float* ws_out = (float*)d_ws;                                   // 8.39 MB
  float* ws_lse = ws_out + (size_t)NPART * PSTRIDE * NDV;         // 64 KB
  float* cntf   = ws_lse + NPART * PSTRIDE;                       // 512 KB

  build_counts<<<NR * NB, 256, 0, stream>>>(kv_lens, bt, cntf);
  attn_partial<<<NR * NKVH * NCH * 2, 256, 0, stream>>>(
      q, k_cache, v_cache, cntf, ws_out, ws_lse);
  attn_combine<<<NB * NKVH * NG, NDV, 0, stream>>>(ws_out, ws_lse, out);
}

// Round 12
// 68.546 us; speedup vs baseline: 1.8621x; 1.0525x over previous
//
#include <hip/hip_runtime.h>
#include <hip/hip_bf16.h>
#include <math.h>

#define NR 8
#define NB 8
#define NH 32
#define NKVH 8
#define NG 4
#define ND 128
#define NDV 128
#define NPAGE 2048
#define KSTR (NKVH*ND)        // 1024 floats per page (all kvh slices)
#define NCH 8                 // page-chunks per rank
#define CHUNK 256             // pages per chunk
#define NPART (NR*NCH)        // 64 partial slots
#define PSTRIDE (NB*NKVH*NG)  // 256 output rows
#define QSCALE 0.088388347648318447f
#define DEFER_THR 8.0f

typedef __attribute__((ext_vector_type(8))) short bf16x8;
typedef __attribute__((ext_vector_type(4))) float f32x4;

static __device__ __forceinline__ short f2bf(float x) {
  __hip_bfloat16 h = __float2bfloat16(x);
  return __builtin_bit_cast(short, h);
}

// async global->LDS, 16B per lane; LDS dest = wave-uniform base + lane*16
static __device__ __forceinline__ void gload_lds16(const float* g, float* l) {
  __builtin_amdgcn_global_load_lds(
      (__attribute__((address_space(1))) void*)g,
      (__attribute__((address_space(3))) void*)l, 16, 0, 0);
}

// ---------------- histogram: cntf[r][b][pg] = (float) multiplicity
__global__ __launch_bounds__(256) void build_counts(
    const int* __restrict__ kv_lens, const int* __restrict__ bt_all,
    float* __restrict__ cntf) {
  const int rb = blockIdx.x;             // r*NB + b
  __shared__ int h[NPAGE];
  for (int i = threadIdx.x; i < NPAGE; i += 256) h[i] = 0;
  __syncthreads();
  const int len = kv_lens[rb];
  const int* bt = bt_all + (size_t)rb * NPAGE;
  for (int i = threadIdx.x; i < len; i += 256) atomicAdd(&h[bt[i]], 1);
  __syncthreads();
  float* o = cntf + (size_t)rb * NPAGE;
  for (int i = threadIdx.x; i < NPAGE; i += 256) o[i] = (float)h[i];
}

// ---------------- MFMA weighted-stream attention partials, 2-deep pipelined.
// block = (r, kvh, chunk, gp); 4 waves, each owns 64 pages (4 tiles of 16).
// PV ownership: lane (col,hq) owns qrows hq*4..+3 x dims {col*4..+3, 64+col*4..+3}
// -> V reads are 2x ds_read_b128/page (2-way banks, free) = 32 DS/tile vs 128.
// Rescale factors stay in-register (softmax rows == PV rows).
__global__ __launch_bounds__(256, 1) void attn_partial(
    const float* __restrict__ q,
    const float* __restrict__ k_cache,
    const float* __restrict__ v_cache,
    const float* __restrict__ cntf,
    float* __restrict__ ws_out,   // [NPART][NB][NKVH][NG][NDV]
    float* __restrict__ ws_lse)   // [NPART][NB][NKVH][NG]
{
  const int bid   = blockIdx.x;
  const int r     = bid & 7;              // XCD swizzle: rank pinned per XCD
  const int kvh   = (bid >> 3) & 7;
  const int chunk = (bid >> 6) & 7;
  const int gp    = bid >> 9;             // heads {2gp, 2gp+1}

  const int tid  = threadIdx.x;
  const int wid  = tid >> 6;
  const int lane = tid & 63;
  const int col  = lane & 15;     // score: page-in-tile | PV: dim-block
  const int hq   = lane >> 4;     // score: k-quarter    | PV: qrow-quad

  // V double-buffer (wave-private), union'd with the post-loop Sacc merge
  // buffer (disjoint lifetimes): 64 KB.
  __shared__ float UN[4][2][2048];
  __shared__ float Plds[4][16][20];       // [pg][qr], stride 20 (16B-aligned)
  __shared__ float Sml[4][16][2];

  // ---- Q A-frags (bf16, pre-scaled)
  bf16x8 qf[4];
  {
    const int qrow = col;
    const int b = qrow & 7;
    const int g = gp * 2 + (qrow >> 3);
    const float* qp = q + ((size_t)b * NH + kvh * NG + g) * ND + hq * 8;
#pragma unroll
    for (int st = 0; st < 4; ++st) {
      const float4 t0 = *(const float4*)(qp + st * 32);
      const float4 t1 = *(const float4*)(qp + st * 32 + 4);
      bf16x8 f;
      f[0] = f2bf(t0.x * QSCALE); f[1] = f2bf(t0.y * QSCALE);
      f[2] = f2bf(t0.z * QSCALE); f[3] = f2bf(t0.w * QSCALE);
      f[4] = f2bf(t1.x * QSCALE); f[5] = f2bf(t1.y * QSCALE);
      f[6] = f2bf(t1.z * QSCALE); f[7] = f2bf(t1.w * QSCALE);
      qf[st] = f;
    }
  }

  const int pg0w = chunk * CHUNK + wid * 64;   // wave's first page
  const float* Kb = k_cache + (size_t)r * NPAGE * KSTR + kvh * ND;
  const float* Vb = v_cache + (size_t)r * NPAGE * KSTR + kvh * NDV;

  // prefetch macros: 8 stage + 8 K + 4 cw = 20 VMEM ops per tile
#define STAGE_V(bf, pgt)                                                     \
  {                                                                          \
    _Pragma("unroll")                                                        \
    for (int i = 0; i < 8; ++i) {                                            \
      const float* s_ =                                                      \
          Vb + (size_t)((pgt) + 2 * i + (lane >> 5)) * KSTR + (lane & 31) * 4; \
      gload_lds16(s_, &UN[wid][bf][i * 256]);                                \
    }                                                                        \
  }
#define KLOAD(dst, pgt)                                                      \
  {                                                                          \
    const float* kp_ = Kb + (size_t)((pgt) + col) * KSTR + hq * 8;           \
    _Pragma("unroll")                                                        \
    for (int st = 0; st < 4; ++st) {                                         \
      dst[2 * st]     = *(const float4*)(kp_ + st * 32);                     \
      dst[2 * st + 1] = *(const float4*)(kp_ + st * 32 + 4);                 \
    }                                                                        \
  }
#define CWLOAD(dst, pgt)                                                     \
  {                                                                          \
    _Pragma("unroll")                                                        \
    for (int rg = 0; rg < 4; ++rg)                                           \
      dst[rg] = cntf[((size_t)(r * NB + ((hq * 4 + rg) & 7))) * NPAGE +      \
                     (pgt) + col];                                           \
  }

  float4 kr[2][8];
  float  cwl[2][4];

  // prologue: prefetch tile 0
  STAGE_V(0, pg0w);
  KLOAD(kr[0], pg0w);
  CWLOAD(cwl[0], pg0w);

  float m[4], l[4];
#pragma unroll
  for (int g4 = 0; g4 < 4; ++g4) { m[g4] = -INFINITY; l[g4] = 0.f; }
  f32x4 O[4][2];                 // [rg][half]: rows hq*4+rg, dims col*4 / 64+col*4
#pragma unroll
  for (int rg = 0; rg < 4; ++rg) {
    O[rg][0] = (f32x4){0.f, 0.f, 0.f, 0.f};
    O[rg][1] = (f32x4){0.f, 0.f, 0.f, 0.f};
  }

#pragma unroll
  for (int t = 0; t < 4; ++t) {
    const int pgt = pg0w + t * 16;
    const int bf  = t & 1;

    if (t < 3) {                         // prefetch t+1, then counted wait
      STAGE_V(bf ^ 1, pgt + 16);
      KLOAD(kr[(t + 1) & 1], pgt + 16);
      CWLOAD(cwl[(t + 1) & 1], pgt + 16);
      asm volatile("s_waitcnt vmcnt(20)" ::: "memory");
    } else {
      asm volatile("s_waitcnt vmcnt(0)" ::: "memory");
    }

    // ---- QK^T: 4 MFMAs (K from prefetched regs, cvt to bf16 now)
    f32x4 acc = (f32x4){0.f, 0.f, 0.f, 0.f};
#pragma unroll
    for (int st = 0; st < 4; ++st) {
      const float4 a0 = kr[bf][2 * st];
      const float4 a1 = kr[bf][2 * st + 1];
      bf16x8 kf;
      kf[0] = f2bf(a0.x); kf[1] = f2bf(a0.y); kf[2] = f2bf(a0.z); kf[3] = f2bf(a0.w);
      kf[4] = f2bf(a1.x); kf[5] = f2bf(a1.y); kf[6] = f2bf(a1.z); kf[7] = f2bf(a1.w);
      acc = __builtin_amdgcn_mfma_f32_16x16x32_bf16(qf[st], kf, acc, 0, 0, 0);
    }

    // ---- batched softmax (counts as weights), defer-max.
    // s[rg] is score of qrow hq*4+rg, page col; row stats uniform across col.
    float s[4], tm[4];
#pragma unroll
    for (int rg = 0; rg < 4; ++rg) { s[rg] = acc[rg]; tm[rg] = acc[rg]; }
#pragma unroll
    for (int mk = 1; mk <= 8; mk <<= 1)
#pragma unroll
      for (int rg = 0; rg < 4; ++rg) tm[rg] = fmaxf(tm[rg], __shfl_xor(tm[rg], mk));

    bool need = false;
#pragma unroll
    for (int rg = 0; rg < 4; ++rg) need |= (tm[rg] > m[rg] + DEFER_THR);
    const bool doresc = __any(need);
    float sc[4];
    if (doresc) {
#pragma unroll
      for (int rg = 0; rg < 4; ++rg) {
        const float mn = fmaxf(m[rg], tm[rg]);
        sc[rg] = __expf(m[rg] - mn);     // first tile: exp(-inf)=0
        m[rg] = mn; l[rg] *= sc[rg];
      }
    }

    float p[4], ts[4];
#pragma unroll
    for (int rg = 0; rg < 4; ++rg) {
      p[rg] = cwl[bf][rg] * __expf(s[rg] - m[rg]);
      ts[rg] = p[rg];
    }
#pragma unroll
    for (int mk = 1; mk <= 8; mk <<= 1)
#pragma unroll
      for (int rg = 0; rg < 4; ++rg) ts[rg] += __shfl_xor(ts[rg], mk);
#pragma unroll
    for (int rg = 0; rg < 4; ++rg) l[rg] += ts[rg];

    // P -> LDS: one b128 per wave (rows hq*4..+3 contiguous in row pg=col)
    {
      f32x4 pv = (f32x4){p[0], p[1], p[2], p[3]};
      *(f32x4*)&Plds[wid][col][hq * 4] = pv;
    }

    if (doresc) {                        // O rows == softmax rows: sc in-register
#pragma unroll
      for (int rg = 0; rg < 4; ++rg) {
        O[rg][0] *= sc[rg];
        O[rg][1] *= sc[rg];
      }
    }

    // ---- PV from LDS-staged V: 3 DS reads per page (2 V + 1 P)
#pragma unroll 4
    for (int pg = 0; pg < 16; ++pg) {
      const f32x4 pw = *(const f32x4*)&Plds[wid][pg][hq * 4];
      const float* vl = &UN[wid][bf][pg * 128 + col * 4];
      const f32x4 va = *(const f32x4*)vl;
      const f32x4 vb2 = *(const f32x4*)(vl + 64);
#pragma unroll
      for (int rg = 0; rg < 4; ++rg) {
        O[rg][0] += pw[rg] * va;
        O[rg][1] += pw[rg] * vb2;
      }
    }
  }

  // ---- merge: overlay Sacc onto the (now dead) V buffers
  __syncthreads();                       // all waves done reading UN
  float* Sacc = &UN[0][0][0];            // rows of 132 floats: [w*16+qr]
  if (col == 0) {
#pragma unroll
    for (int rg = 0; rg < 4; ++rg) {
      Sml[wid][hq * 4 + rg][0] = m[rg];
      Sml[wid][hq * 4 + rg][1] = l[rg];
    }
  }
#pragma unroll
  for (int rg = 0; rg < 4; ++rg) {
    const int qr = hq * 4 + rg;
    *(f32x4*)&Sacc[(wid * 16 + qr) * 132 + col * 4]      = O[rg][0];
    *(f32x4*)&Sacc[(wid * 16 + qr) * 132 + 64 + col * 4] = O[rg][1];
  }
  __syncthreads();

  // ---- 4-way wave merge, normalize, write partial
  const int qr = tid >> 4;        // 0..15
  const int db = tid & 15;        // 8 dims each
  float M = -INFINITY;
#pragma unroll
  for (int w = 0; w < 4; ++w) M = fmaxf(M, Sml[w][qr][0]);
  float wgt[4];
  float L = 0.f;
#pragma unroll
  for (int w = 0; w < 4; ++w) {
    const float mw = Sml[w][qr][0];
    wgt[w] = (mw > -1e37f) ? __expf(mw - M) : 0.f;
    L += Sml[w][qr][1] * wgt[w];
  }
  const float inv = (L > 0.f) ? 1.f / L : 0.f;

  const int pi = r * NCH + chunk;
  const int b  = qr & 7;
  const int g  = gp * 2 + (qr >> 3);
  const size_t prow = (((size_t)pi * NB + b) * NKVH + kvh) * NG + g;
  float* orow = ws_out + prow * NDV + db * 8;
#pragma unroll
  for (int x = 0; x < 2; ++x) {
    float4 o = make_float4(0.f, 0.f, 0.f, 0.f);
#pragma unroll
    for (int w = 0; w < 4; ++w) {
      const float* s4 = &Sacc[(w * 16 + qr) * 132 + db * 8 + x * 4];
      o.x += s4[0] * wgt[w]; o.y += s4[1] * wgt[w];
      o.z += s4[2] * wgt[w]; o.w += s4[3] * wgt[w];
    }
    o.x *= inv; o.y *= inv; o.z *= inv; o.w *= inv;
    *(float4*)(orow + x * 4) = o;
  }
  if (db == 0) ws_lse[prow] = (L > 0.f) ? (M + __logf(L)) : -1e30f;
}

// ---------------- combine over NPART partials per (b,kvh,g)
__global__ __launch_bounds__(128) void attn_combine(
    const float* __restrict__ ws_out,
    const float* __restrict__ ws_lse,
    float* __restrict__ out)
{
  const int bkg = blockIdx.x;
  const int d   = threadIdx.x;

  float mg = -INFINITY;
#pragma unroll 16
  for (int p = 0; p < NPART; ++p)
    mg = fmaxf(mg, ws_lse[p * PSTRIDE + bkg]);

  float denom = 0.f, acc = 0.f;
#pragma unroll 8
  for (int p = 0; p < NPART; ++p) {
    const float e = __expf(ws_lse[p * PSTRIDE + bkg] - mg);
    denom += e;
    acc += e * ws_out[((size_t)p * PSTRIDE + bkg) * NDV + d];
  }
  out[(size_t)bkg * NDV + d] = acc / denom;
}

extern "C" void kernel_launch(void* const* d_in, const int* in_sizes, int n_in,
                              void* d_out, int out_size, void* d_ws, size_t ws_size,
                              hipStream_t stream) {
  const float* q        = (const float*)d_in[0];
  const float* k_cache  = (const float*)d_in[1];
  const float* v_cache  = (const float*)d_in[2];
  const int*   kv_lens  = (const int*)d_in[3];
  const int*   bt       = (const int*)d_in[4];
  float* out = (float*)d_out;

  float* ws_out = (float*)d_ws;                                   // 8.39 MB
  float* ws_lse = ws_out + (size_t)NPART * PSTRIDE * NDV;         // 64 KB
  float* cntf   = ws_lse + NPART * PSTRIDE;                       // 512 KB

  build_counts<<<NR * NB, 256, 0, stream>>>(kv_lens, bt, cntf);
  attn_partial<<<NR * NKVH * NCH * 2, 256, 0, stream>>>(
      q, k_cache, v_cache, cntf, ws_out, ws_lse);
  attn_combine<<<NB * NKVH * NG, NDV, 0, stream>>>(ws_out, ws_lse, out);
}